// Round 7
// baseline (421.317 us; speedup 1.0000x reference)
//
#include <hip/hip_runtime.h>
#include <math.h>

static constexpr int   B_   = 8;
static constexpr int   N_   = 2048;   // points per set
static constexpr int   TPB  = 256;
static constexpr int   TILE = 32;     // rows/cols owned per block
static constexpr int   BPB  = 64;     // blocks per batch
static constexpr int   NBLK = B_ * BPB;   // 512
static constexpr int   BN   = B_ * N_;
static constexpr float EPS_ = 1e-9f;
static constexpr float LOG2E = 1.4426950408889634f;

#define SCOPE_A __HIP_MEMORY_SCOPE_AGENT

// ws layout (floats):
//  X1   [4*BN]  packed xyz1 (x,y,z,|p|^2)   read-only after init (cached reads)
//  X2   [4*BN]  packed xyz2                 read-only after init
//  LSCAL[BN]  LSATR[BN]  LWR[BN]  WR[BN]    cross-block state (atomic sc-ops)
//  COSTP[NBLK]                              per-tile cost partials
//  BAR  [8*64 u32]                          per-batch monotonic barrier counters
#define WS_X1    (ws)
#define WS_X2    (ws + 4*BN)
#define WS_LSCAL (ws + 8*BN)
#define WS_LSATR (ws + 9*BN)
#define WS_LWR   (ws + 10*BN)
#define WS_WR    (ws + 11*BN)
#define WS_COSTP (ws + 12*BN)
#define WS_BARU  ((unsigned*)(ws + 12*BN + NBLK))

__device__ __constant__ float c_lvl[11] = {
    -65536.f*LOG2E, -16384.f*LOG2E, -4096.f*LOG2E, -1024.f*LOG2E,
    -256.f*LOG2E,   -64.f*LOG2E,    -16.f*LOG2E,   -4.f*LOG2E,
    -1.f*LOG2E,     -0.25f*LOG2E,   0.f };

__device__ __forceinline__ float aload(const float* p) {
    return __hip_atomic_load(p, __ATOMIC_RELAXED, SCOPE_A);
}
__device__ __forceinline__ void astore(float* p, float v) {
    __hip_atomic_store(p, v, __ATOMIC_RELAXED, SCOPE_A);
}

__global__ void __launch_bounds__(TPB)
emd_init(const float* __restrict__ xyz1, const float* __restrict__ xyz2,
         float* __restrict__ ws)
{
    const int idx = blockIdx.x * TPB + threadIdx.x;
    if (idx < BN) {
        float x = xyz1[idx*3], y = xyz1[idx*3+1], z = xyz1[idx*3+2];
        reinterpret_cast<float4*>(WS_X1)[idx] =
            make_float4(x, y, z, fmaf(x,x, fmaf(y,y, z*z)));
        x = xyz2[idx*3]; y = xyz2[idx*3+1]; z = xyz2[idx*3+2];
        reinterpret_cast<float4*>(WS_X2)[idx] =
            make_float4(x, y, z, fmaf(x,x, fmaf(y,y, z*z)));
        WS_LSATR[idx] = 0.f;    // log2(satr=1)
    }
    if (idx < 8 * 64) WS_BARU[idx] = 0u;   // barrier counters (each launch!)
}

// fence-free per-batch barrier: monotonic counter, relaxed polls, one
// release-RMW arrival, workgroup-scope acquire fence (compiler order only).
__device__ __forceinline__ void bbar(unsigned* cnt, unsigned target)
{
    __syncthreads();
    if (threadIdx.x == 0) {
        __hip_atomic_fetch_add(cnt, 1u, __ATOMIC_RELEASE, SCOPE_A);
        int spins = 0;
        while (__hip_atomic_load(cnt, __ATOMIC_RELAXED, SCOPE_A) < target) {
            __builtin_amdgcn_s_sleep(4);
            if (++spins > (1 << 17)) break;   // tripwire: fail visibly, no hang
        }
        __builtin_amdgcn_fence(__ATOMIC_ACQUIRE, "workgroup");
    }
    __syncthreads();
}

// two-stage block reduction over red overlay; valid result in t < TILE
__device__ __forceinline__ float block_reduce(
    float (*red)[33], float (*red2)[33], const float (&arr)[8], int t)
{
    const int g = t & 3, c = t >> 2;
    __syncthreads();                       // pts overlay safety
#pragma unroll
    for (int j = 0; j < 8; ++j) red[c][g * 8 + j] = arr[j];
    __syncthreads();
    { const int o = t & 31, sg = t >> 5; float a = 0.f;
#pragma unroll
      for (int k = 0; k < 8; ++k) a += red[sg * 8 + k][o];
      red2[sg][o] = a; }
    __syncthreads();
    float dst = 0.f;
    if (t < TILE) {
#pragma unroll
        for (int sg = 0; sg < 8; ++sg) dst += red2[sg][t];
    }
    return dst;
}

// MODE 0/1: s1 += exp2(k.p + p.w)  (aux prefolded into pts.w at staging)
// MODE 2  : s1 += eA, s2 += eA*sqrt(d2), s3 += eB
// MODE 3  : s2 += p.w * sqrt(d2)   (p.w = raw wr)
template<int MODE>
__device__ __forceinline__ void sweep(
    const float4* pts, const float2* aux2,
    const float (&kx)[8], const float (&ky)[8], const float (&kz)[8],
    const float (&kq)[8], float lvlA, float lvlB, int t,
    float (&s1)[8], float (&s2)[8], float (&s3)[8])
{
#pragma unroll
    for (int j = 0; j < 8; ++j) { s1[j] = 0.f; s2[j] = 0.f; s3[j] = 0.f; }
    int l = t >> 2;
    float4 p = pts[l];
    float2 a;
    if (MODE == 2) a = aux2[l];

    if (MODE == 0 || MODE == 1) {
#pragma unroll 4
        for (int i = 0; i < 32; ++i) {
            const int ln = (l + 64) & (N_ - 1);
            const float4 pn = pts[ln];
#pragma unroll
            for (int j = 0; j < 8; ++j) {
                const float arg = fmaf(kx[j], p.x, fmaf(ky[j], p.y,
                                  fmaf(kz[j], p.z, p.w + kq[j])));
                s1[j] += __builtin_amdgcn_exp2f(arg);
            }
            p = pn; l = ln;
        }
    } else if (MODE == 2) {
#pragma unroll 2
        for (int i = 0; i < 32; ++i) {
            const int ln = (l + 64) & (N_ - 1);
            const float4 pn = pts[ln];
            const float2 an = aux2[ln];
#pragma unroll
            for (int j = 0; j < 8; ++j) {
                const float dq = fmaf(kx[j], p.x, fmaf(ky[j], p.y,
                                 fmaf(kz[j], p.z, kq[j])));
                const float d2 = p.w + dq;
                const float sq = __builtin_amdgcn_sqrtf(fmaxf(d2, 0.f));
                const float eA = __builtin_amdgcn_exp2f(fmaf(lvlA, dq, a.x));
                const float eB = __builtin_amdgcn_exp2f(fmaf(lvlB, dq, a.y));
                s1[j] += eA;
                s2[j]  = fmaf(eA, sq, s2[j]);
                s3[j] += eB;
            }
            p = pn; a = an; l = ln;
        }
    } else {
#pragma unroll 4
        for (int i = 0; i < 32; ++i) {
            const int ln = (l + 64) & (N_ - 1);
            const float4 pn = pts[ln];
#pragma unroll
            for (int j = 0; j < 8; ++j) {
                const float dx = p.x - kx[j], dy = p.y - ky[j], dz = p.z - kz[j];
                const float d2 = fmaf(dx, dx, fmaf(dy, dy, dz * dz));
                s2[j] = fmaf(p.w, __builtin_amdgcn_sqrtf(fmaxf(d2, 0.f)), s2[j]);
            }
            p = pn; l = ln;
        }
    }
}

__global__ void __launch_bounds__(TPB, 2)
emd_main(float* __restrict__ ws, float* __restrict__ out)
{
    __shared__ __align__(16) float4 pts[N_];    // 32 KB
    __shared__ __align__(16) float2 aux2[N_];   // 16 KB (MODE 2 only)
    float (*red)[33]  = reinterpret_cast<float(*)[33]>(pts);
    float (*red2)[33] = reinterpret_cast<float(*)[33]>(
                            reinterpret_cast<char*>(pts) + 64*33*4);

    const int b    = blockIdx.x & 7;    // XCD-locality heuristic (perf only)
    const int tile = blockIdx.x >> 3;
    const int t    = threadIdx.x;
    const int g    = t & 3;

    unsigned* cnt = WS_BARU + b * 64;   // 256-B separated per batch
    unsigned  phase = 0;

    const float4* x1v = reinterpret_cast<const float4*>(WS_X1) + b * N_;
    const float4* x2v = reinterpret_cast<const float4*>(WS_X2) + b * N_;
    float* lscal = WS_LSCAL + b * N_;
    float* lsatr = WS_LSATR + b * N_;
    float* lwr   = WS_LWR   + b * N_;
    float* wrp   = WS_WR    + b * N_;

    // owned coords: rows (set 1) and cols (set 2)
    float rx[8], ry[8], rz[8], rq[8], ox[8], oy[8], oz[8], oq[8];
    {
        const int ob = tile * TILE + g * 8;
#pragma unroll
        for (int j = 0; j < 8; ++j) {
            float4 v = x1v[ob + j];
            rx[j] = v.x; ry[j] = v.y; rz[j] = v.z; rq[j] = v.w;
            float4 w = x2v[ob + j];
            ox[j] = w.x; oy[j] = w.y; oz[j] = w.z; oq[j] = w.w;
        }
    }

    float satl = 1.f, satr = 1.f, mysc = 0.f, cost = 0.f;   // valid t < 32
    const int gi = tile * TILE + t;     // batch-local index for t<32 epilogues
    float s1[8], s2[8], s3[8];
    float kx[8], ky[8], kz[8], kq[8];

    // ============ M0: level-0 row sweep -> scale ============
    {
        const float lv = c_lvl[0];
        for (int p = t; p < N_; p += TPB) {
            float4 v = x2v[p];
            pts[p] = make_float4(v.x, v.y, v.z, fmaf(lv, v.w, aload(lsatr + p)));
        }
#pragma unroll
        for (int j = 0; j < 8; ++j) {
            const float m2 = -2.f * lv;
            kx[j] = m2*rx[j]; ky[j] = m2*ry[j]; kz[j] = m2*rz[j]; kq[j] = lv*rq[j];
        }
        __syncthreads();
        sweep<0>(pts, aux2, kx, ky, kz, kq, 0.f, 0.f, t, s1, s2, s3);
        const float rs1 = block_reduce(red, red2, s1, t);
        if (t < TILE) {
            mysc = satl / (rs1 + EPS_);
            astore(lscal + gi, __log2f(mysc));
        }
        bbar(cnt, BPB * ++phase);
    }

    for (int lev = 0; lev <= 10; ++lev) {
        // ============ M1: col sweep at lev ============
        {
            const float lv = c_lvl[lev];
            for (int p = t; p < N_; p += TPB) {
                float4 v = x1v[p];
                pts[p] = make_float4(v.x, v.y, v.z,
                                     fmaf(lv, v.w, aload(lscal + p)));
            }
#pragma unroll
            for (int j = 0; j < 8; ++j) {
                const float m2 = -2.f * lv;
                kx[j] = m2*ox[j]; ky[j] = m2*oy[j]; kz[j] = m2*oz[j];
                kq[j] = lv*oq[j];
            }
            __syncthreads();
            sweep<1>(pts, aux2, kx, ky, kz, kq, 0.f, 0.f, t, s1, s2, s3);
            const float rs1 = block_reduce(red, red2, s1, t);
            if (t < TILE) {
                const float w1s = satr * rs1;
                const float rr  = fminf(satr / (w1s + EPS_), 1.f);
                const float wrv = satr * rr;
                satr = fmaxf(satr - rr * w1s, 0.f);
                astore(wrp   + gi, wrv);
                astore(lwr   + gi, __log2f(wrv));
                astore(lsatr + gi, __log2f(satr));
            }
            bbar(cnt, BPB * ++phase);
        }

        if (lev < 10) {
            // ===== M2: merged P3(lev) + P1(lev+1) row sweep =====
            const float lvA = c_lvl[lev], lvB = c_lvl[lev + 1];
            for (int p = t; p < N_; p += TPB) {
                float4 v = x2v[p];
                pts[p]  = v;
                aux2[p] = make_float2(fmaf(lvA, v.w, aload(lwr + p)),
                                      fmaf(lvB, v.w, aload(lsatr + p)));
            }
#pragma unroll
            for (int j = 0; j < 8; ++j) {
                kx[j] = -2.f*rx[j]; ky[j] = -2.f*ry[j]; kz[j] = -2.f*rz[j];
                kq[j] = rq[j];
            }
            __syncthreads();
            sweep<2>(pts, aux2, kx, ky, kz, kq, lvA, lvB, t, s1, s2, s3);
            const float rs1 = block_reduce(red, red2, s1, t);
            const float rs2 = block_reduce(red, red2, s2, t);
            const float rs3 = block_reduce(red, red2, s3, t);
            if (t < TILE) {
                satl = fmaxf(satl - mysc * rs1, 0.f);
                cost = fmaf(mysc, rs2, cost);
                mysc = satl / (rs3 + EPS_);
                astore(lscal + gi, __log2f(mysc));
            }
            bbar(cnt, BPB * ++phase);
        } else {
            // ===== M3: final row sweep (lvl = 0 -> weight = raw wr) =====
            for (int p = t; p < N_; p += TPB) {
                float4 v = x2v[p];
                pts[p] = make_float4(v.x, v.y, v.z, aload(wrp + p));
            }
#pragma unroll
            for (int j = 0; j < 8; ++j) {
                kx[j] = rx[j]; ky[j] = ry[j]; kz[j] = rz[j]; kq[j] = 0.f;
            }
            __syncthreads();
            sweep<3>(pts, aux2, kx, ky, kz, kq, 0.f, 0.f, t, s1, s2, s3);
            const float rs2 = block_reduce(red, red2, s2, t);
            if (t < 64) {
                float v = (t < TILE) ? fmaf(mysc, rs2, cost) : 0.f;
#pragma unroll
                for (int k = 16; k >= 1; k >>= 1) v += __shfl_xor(v, k, 32);
                if (t == 0) astore(WS_COSTP + b * BPB + tile, v);
            }
            bbar(cnt, BPB * ++phase);
            if (tile == 0 && t < 64) {
                float v = aload(WS_COSTP + b * BPB + t);
#pragma unroll
                for (int k = 32; k >= 1; k >>= 1) v += __shfl_xor(v, k, 64);
                if (t == 0) out[b] = v;
            }
        }
    }
}

extern "C" void kernel_launch(void* const* d_in, const int* in_sizes, int n_in,
                              void* d_out, int out_size, void* d_ws, size_t ws_size,
                              hipStream_t stream)
{
    const float* xyz1 = (const float*)d_in[0];
    const float* xyz2 = (const float*)d_in[1];
    float* out = (float*)d_out;
    float* ws  = (float*)d_ws;

    emd_init<<<BN / TPB, TPB, 0, stream>>>(xyz1, xyz2, ws);
    emd_main<<<NBLK, TPB, 0, stream>>>(ws, out);
}